// Round 2
// baseline (3371.730 us; speedup 1.0000x reference)
//
#include <hip/hip_runtime.h>
#include <math.h>

// Problem constants
#define BATCH   256
#define T_STEPS 4096
#define IN_DIM  28
#define HID     128
#define GATES   512   // 4*HID
#define OUT_DIM 10

__device__ __forceinline__ float frcp_fast(float x) {
    return __builtin_amdgcn_rcpf(x);
}

__device__ __forceinline__ float sigm(float x) {
    // 1/(1+exp(-x)); exp(-x)->inf for very negative x gives 0, ->0 gives 1. Safe.
    return frcp_fast(1.0f + __expf(-x));
}

__device__ __forceinline__ float tanh_fast(float x) {
    // tanh(x) = sign(x) * (1 - e) / (1 + e), e = exp(-2|x|)  (no overflow)
    float ax = fabsf(x);
    float e  = __expf(-2.0f * ax);
    float r  = (1.0f - e) * frcp_fast(1.0f + e);
    return copysignf(r, x);
}

// ---------------------------------------------------------------------------
// Kernel 1: input projection for batch element 255 only.
// gx[t, g] = dot(x255[t, :], w_ih[g, :]) + b_ih[g] + b_hh[g]
// ---------------------------------------------------------------------------
__global__ __launch_bounds__(GATES) void k_inproj(const float* __restrict__ x255,
                                                  const float* __restrict__ w_ih,
                                                  const float* __restrict__ b_ih,
                                                  const float* __restrict__ b_hh,
                                                  float* __restrict__ gx) {
    const int t = blockIdx.x;
    const int g = threadIdx.x;
    __shared__ float xs[IN_DIM];
    if (g < IN_DIM) xs[g] = x255[t * IN_DIM + g];
    __syncthreads();
    float acc = b_ih[g] + b_hh[g];
    const float* __restrict__ wr = w_ih + g * IN_DIM;
#pragma unroll
    for (int k = 0; k < IN_DIM; ++k) acc += wr[k] * xs[k];
    gx[t * GATES + g] = acc;
}

// ---------------------------------------------------------------------------
// Kernel 2: the sequential LSTM scan — single workgroup, 512 threads.
// Thread g owns gate-row g; w_hh[g, :] lives in 32 float4 VGPRs.
//
// __launch_bounds__(512, 2): 8 waves = 2 waves/SIMD -> 256 VGPR/wave budget.
// Without the min-waves arg the compiler capped at 80 VGPRs and spilled the
// 128-VGPR weight array to scratch (R0: 4.2 GB FETCH / 2.0 GB WRITE, 3.4 ms).
//
// Per step: preact dot from LDS-broadcast h (uniform-address ds_read_b128,
// conflict-free), per-thread activation, threads 0..127 do the c/h update.
// Two barriers per step.
// ---------------------------------------------------------------------------
template <bool FUSED>
__global__ __launch_bounds__(GATES, 2) void k_scan(const float* __restrict__ gx,
                                                   const float* __restrict__ w_hh,
                                                   float* __restrict__ hs,
                                                   const float* __restrict__ x255,
                                                   const float* __restrict__ w_ih,
                                                   const float* __restrict__ b_ih,
                                                   const float* __restrict__ b_hh) {
    const int g    = threadIdx.x;   // 0..511
    const int quad = g >> 7;        // 0:i 1:f 2:g 3:o

    __shared__ float h_sh[HID];
    __shared__ float act_sh[GATES];
    __shared__ float xs[IN_DIM];

    // Recurrent weights: row g of w_hh, held in registers (32 float4 = 128 VGPR).
    float4 wv[HID / 4];
    const float4* __restrict__ wrow = reinterpret_cast<const float4*>(w_hh + g * HID);
#pragma unroll
    for (int k = 0; k < HID / 4; ++k) wv[k] = wrow[k];

    float wih[FUSED ? IN_DIM : 1];
    float bsum = 0.0f;
    if (FUSED) {
        bsum = b_ih[g] + b_hh[g];
#pragma unroll
        for (int k = 0; k < IN_DIM; ++k) wih[k] = w_ih[g * IN_DIM + k];
    }

    if (g < HID) h_sh[g] = 0.0f;
    float c = 0.0f;     // cell state for unit g (threads 0..127 only use it)
    __syncthreads();

    float gnext = 0.0f;
    if (!FUSED) gnext = gx[g];   // prefetch step 0

    for (int t = 0; t < T_STEPS; ++t) {
        float a0, a1 = 0.0f, a2 = 0.0f, a3 = 0.0f;
        if (FUSED) {
            __syncthreads();   // protect xs from previous step's readers
            if (g < IN_DIM) xs[g] = x255[t * IN_DIM + g];
            __syncthreads();
            float acc = bsum;
#pragma unroll
            for (int k = 0; k < IN_DIM; ++k) acc += wih[k] * xs[k];
            a0 = acc;
        } else {
            a0 = gnext;
            if (t + 1 < T_STEPS) gnext = gx[(t + 1) * GATES + g];  // prefetch next step
        }

        // preact = gx + dot(w_hh[g,:], h)  — h broadcast from LDS (b128, uniform addr)
        const float4* __restrict__ h4 = reinterpret_cast<const float4*>(h_sh);
#pragma unroll
        for (int k = 0; k < HID / 4; ++k) {
            float4 hv = h4[k];
            a0 += wv[k].x * hv.x;
            a1 += wv[k].y * hv.y;
            a2 += wv[k].z * hv.z;
            a3 += wv[k].w * hv.w;
        }
        float pre = (a0 + a1) + (a2 + a3);

        // per-thread activation (gate order i, f, g, o) — quad is wave-uniform
        float a = (quad == 2) ? tanh_fast(pre) : sigm(pre);
        act_sh[g] = a;
        __syncthreads();   // barrier 1: preacts ready; also protects h_sh read->write

        if (g < HID) {
            float iv = act_sh[g];
            float fv = act_sh[HID + g];
            float gv = act_sh[2 * HID + g];
            float ov = act_sh[3 * HID + g];
            c = fv * c + iv * gv;
            float h = ov * tanh_fast(c);
            h_sh[g] = h;
            hs[t * HID + g] = h;   // fire-and-forget global store (512 B/step)
        }
        __syncthreads();   // barrier 2: h ready for next step's dot; act_sh reusable
    }
}

// ---------------------------------------------------------------------------
// Kernel 3: final FC — out[t, o] = dot(hs[t, :], w_fc[o, :]) + b_fc[o]
// ---------------------------------------------------------------------------
__global__ __launch_bounds__(256) void k_fc(const float* __restrict__ hs,
                                            const float* __restrict__ w_fc,
                                            const float* __restrict__ b_fc,
                                            float* __restrict__ out) {
    const int idx = blockIdx.x * blockDim.x + threadIdx.x;
    if (idx >= T_STEPS * OUT_DIM) return;
    const int t = idx / OUT_DIM;
    const int o = idx - t * OUT_DIM;
    const float* __restrict__ hrow = hs + t * HID;
    const float* __restrict__ wrow = w_fc + o * HID;
    float acc = b_fc[o];
#pragma unroll 8
    for (int k = 0; k < HID; ++k) acc += hrow[k] * wrow[k];
    out[idx] = acc;
}

// ---------------------------------------------------------------------------
extern "C" void kernel_launch(void* const* d_in, const int* in_sizes, int n_in,
                              void* d_out, int out_size, void* d_ws, size_t ws_size,
                              hipStream_t stream) {
    const float* x    = (const float*)d_in[0];  // [B, T, I]
    const float* w_ih = (const float*)d_in[1];  // [4H, I]
    const float* w_hh = (const float*)d_in[2];  // [4H, H]
    const float* b_ih = (const float*)d_in[3];  // [4H]
    const float* b_hh = (const float*)d_in[4];  // [4H]
    const float* w_fc = (const float*)d_in[5];  // [OUT, H]
    const float* b_fc = (const float*)d_in[6];  // [OUT]
    float* out = (float*)d_out;                 // [T, OUT]

    // Only batch element B-1 is observable in the reference output.
    const float* x255 = x + (size_t)(BATCH - 1) * T_STEPS * IN_DIM;

    float* hs = (float*)d_ws;                                  // 4096*128 f32 = 2 MB
    float* gxbuf = hs + (size_t)T_STEPS * HID;                 // 4096*512 f32 = 8 MB
    const size_t need_full = (size_t)(T_STEPS * HID + T_STEPS * GATES) * sizeof(float);

    if (ws_size >= need_full) {
        k_inproj<<<T_STEPS, GATES, 0, stream>>>(x255, w_ih, b_ih, b_hh, gxbuf);
        k_scan<false><<<1, GATES, 0, stream>>>(gxbuf, w_hh, hs, x255, w_ih, b_ih, b_hh);
    } else {
        // Fallback: compute input projection inline (needs only the 2 MB hs buffer).
        k_scan<true><<<1, GATES, 0, stream>>>(nullptr, w_hh, hs, x255, w_ih, b_ih, b_hh);
    }

    const int n = T_STEPS * OUT_DIM;
    k_fc<<<(n + 255) / 256, 256, 0, stream>>>(hs, w_fc, b_fc, out);
}

// Round 3
// 3077.608 us; speedup vs baseline: 1.0956x; 1.0956x over previous
//
#include <hip/hip_runtime.h>
#include <hip/hip_bf16.h>
#include <math.h>

// Problem constants
#define BATCH   256
#define T_STEPS 4096
#define IN_DIM  28
#define HID     128
#define GATES   512   // 4*HID
#define OUT_DIM 10

typedef short bf16x8 __attribute__((ext_vector_type(8)));  // 8 bf16 in 4 VGPRs
typedef float f32x4  __attribute__((ext_vector_type(4)));

__device__ __forceinline__ float frcp_fast(float x) {
    return __builtin_amdgcn_rcpf(x);
}

__device__ __forceinline__ float sigm(float x) {
    return frcp_fast(1.0f + __expf(-x));
}

__device__ __forceinline__ float tanh_fast(float x) {
    // tanh(x) = sign(x) * (1 - e) / (1 + e), e = exp(-2|x|)  (no overflow)
    float ax = fabsf(x);
    float e  = __expf(-2.0f * ax);
    float r  = (1.0f - e) * frcp_fast(1.0f + e);
    return copysignf(r, x);
}

__device__ __forceinline__ unsigned short f2bf(float f) {
    __hip_bfloat16 h = __float2bfloat16(f);   // RNE
    return __builtin_bit_cast(unsigned short, h);
}
__device__ __forceinline__ float bf2f(unsigned short u) {
    return __bfloat162float(__builtin_bit_cast(__hip_bfloat16, u));
}

// ---------------------------------------------------------------------------
// Kernel 1: input projection for batch element 255 only.
// gx[t, g] = dot(x255[t, :], w_ih[g, :]) + b_ih[g] + b_hh[g]
// ---------------------------------------------------------------------------
__global__ __launch_bounds__(GATES) void k_inproj(const float* __restrict__ x255,
                                                  const float* __restrict__ w_ih,
                                                  const float* __restrict__ b_ih,
                                                  const float* __restrict__ b_hh,
                                                  float* __restrict__ gx) {
    const int t = blockIdx.x;
    const int g = threadIdx.x;
    __shared__ float xs[IN_DIM];
    if (g < IN_DIM) xs[g] = x255[t * IN_DIM + g];
    __syncthreads();
    float acc = b_ih[g] + b_hh[g];
    const float* __restrict__ wr = w_ih + g * IN_DIM;
#pragma unroll
    for (int k = 0; k < IN_DIM; ++k) acc += wr[k] * xs[k];
    gx[t * GATES + g] = acc;
}

// ---------------------------------------------------------------------------
// Kernel 2 (main): MFMA LSTM scan — single workgroup, 512 threads (8 waves).
//
// preact(512) = W_hh(512x128) @ h(128), via mfma_f32_16x16x32_bf16:
//   A = W tile (bf16, loaded ONCE into 64 VGPRs/lane: 4 m-tiles x 4 k-tiles),
//   B = h replicated across all 16 columns (so B-frag = broadcast LDS read).
// Precision: W single bf16 (preact err ~2-4e-4); h split hi/lo bf16
// (2 MFMA legs share the same W frags) so h-quantization error ~4e-6.
// K-permutation invariance: A and B frags use the same k-indexing, so the
// exact HW k-layout doesn't matter; D layout is the m89-verified
// row=(l>>4)*4+reg, col=l&15 (col-redundant since B cols are identical).
//
// Each lane finalizes exactly 1 gate: q=l>>4 picks the row-group it holds,
// l&15 picks (m-tile, reg). Wave w owns gates [64w, 64w+64) -> the gate
// quadrant (i/f/g/o) is wave-uniform (w>>1): no divergence in activation.
//
// amdgpu_waves_per_eu(2,2): 8 waves = 2/SIMD exactly; VGPR budget 256 so the
// ~160-reg live set (64 W-frags + acc + B-frags) stays register-resident.
// ---------------------------------------------------------------------------
__global__ __attribute__((amdgpu_flat_work_group_size(512, 512),
                          amdgpu_waves_per_eu(2, 2)))
void k_scan_mfma(const float* __restrict__ gx,
                 const float* __restrict__ w_hh,
                 float* __restrict__ hs) {
    const int tid  = threadIdx.x;
    const int w    = tid >> 6;          // wave 0..7
    const int l    = tid & 63;          // lane 0..63
    const int q    = l >> 4;            // row-group 0..3
    const int cidx = l & 15;
    const int mt_sel = cidx >> 2;       // which m-tile this lane finalizes
    const int r_sel  = cidx & 3;        // which acc reg this lane finalizes
    const int gbase  = w * 64;
    const int gate   = gbase + mt_sel * 16 + q * 4 + r_sel;
    const int quad   = w >> 1;          // 0:i 1:f 2:g 3:o (wave-uniform)

    __shared__ __align__(16) unsigned short h_hi[HID];
    __shared__ __align__(16) unsigned short h_lo[HID];
    __shared__ float act_sh[GATES];

    // ---- one-time: W_hh -> bf16 A-fragments in registers (64 VGPRs) ----
    // A-frag for (mt, kt): lane l holds W[row = gbase+mt*16+(l&15)]
    //                                  [k  = kt*32 + (l>>4)*8 + j], j=0..7
    bf16x8 wf[4][4];
#pragma unroll
    for (int mt = 0; mt < 4; ++mt) {
        const int row = gbase + mt * 16 + cidx;
        const float* __restrict__ wr = w_hh + row * HID;
#pragma unroll
        for (int kt = 0; kt < 4; ++kt) {
            const int k0 = kt * 32 + q * 8;
            bf16x8 v;
#pragma unroll
            for (int j = 0; j < 8; ++j) v[j] = (short)f2bf(wr[k0 + j]);
            wf[mt][kt] = v;
        }
    }

    if (tid < HID) { h_hi[tid] = 0; h_lo[tid] = 0; }
    float c = 0.0f;                     // cell state (threads 0..127)
    float gnext = gx[gate];             // prefetch step 0
    __syncthreads();

    for (int t = 0; t < T_STEPS; ++t) {
        // B-frags: h replicated across cols -> per-group broadcast b128 reads
        bf16x8 bh[4], bl[4];
#pragma unroll
        for (int kt = 0; kt < 4; ++kt) {
            bh[kt] = *reinterpret_cast<const bf16x8*>(&h_hi[kt * 32 + q * 8]);
            bl[kt] = *reinterpret_cast<const bf16x8*>(&h_lo[kt * 32 + q * 8]);
        }

        // 32 MFMAs: 4 m-tiles x 4 k-tiles x 2 legs (hi/lo share W frags)
        f32x4 acc[4];
#pragma unroll
        for (int mt = 0; mt < 4; ++mt) {
            f32x4 a = {0.f, 0.f, 0.f, 0.f};
#pragma unroll
            for (int kt = 0; kt < 4; ++kt) {
                a = __builtin_amdgcn_mfma_f32_16x16x32_bf16(wf[mt][kt], bh[kt], a, 0, 0, 0);
                a = __builtin_amdgcn_mfma_f32_16x16x32_bf16(wf[mt][kt], bl[kt], a, 0, 0, 0);
            }
            acc[mt] = a;
        }

        // pick this lane's gate (static indices only — no scratch)
        float pre = 0.0f;
#pragma unroll
        for (int mt = 0; mt < 4; ++mt)
#pragma unroll
            for (int r = 0; r < 4; ++r)
                if (mt == mt_sel && r == r_sel) pre = acc[mt][r];

        pre += gnext;
        if (t + 1 < T_STEPS) gnext = gx[(t + 1) * GATES + gate];  // prefetch

        float a = (quad == 2) ? tanh_fast(pre) : sigm(pre);
        act_sh[gate] = a;
        __syncthreads();   // barrier 1: all acts visible

        if (tid < HID) {
            float iv = act_sh[tid];
            float fv = act_sh[HID + tid];
            float gv = act_sh[2 * HID + tid];
            float ov = act_sh[3 * HID + tid];
            c = fv * c + iv * gv;
            float h = ov * tanh_fast(c);
            hs[t * HID + tid] = h;
            unsigned short hi = f2bf(h);
            h_hi[tid] = hi;
            h_lo[tid] = f2bf(h - bf2f(hi));   // residual: h to ~2^-18
        }
        __syncthreads();   // barrier 2: h_hi/h_lo ready for next step
    }
}

// ---------------------------------------------------------------------------
// Fallback scan (fused input projection, f32 VALU) — used only if d_ws is too
// small for the gx buffer. Known-good at ~3.4 ms.
// ---------------------------------------------------------------------------
__global__ __launch_bounds__(GATES) void k_scan_valu(const float* __restrict__ w_hh,
                                                     float* __restrict__ hs,
                                                     const float* __restrict__ x255,
                                                     const float* __restrict__ w_ih,
                                                     const float* __restrict__ b_ih,
                                                     const float* __restrict__ b_hh) {
    const int g    = threadIdx.x;
    const int quad = g >> 7;

    __shared__ float h_sh[HID];
    __shared__ float act_sh[GATES];
    __shared__ float xs[IN_DIM];

    float4 wv[HID / 4];
    const float4* __restrict__ wrow = reinterpret_cast<const float4*>(w_hh + g * HID);
#pragma unroll
    for (int k = 0; k < HID / 4; ++k) wv[k] = wrow[k];

    float bsum = b_ih[g] + b_hh[g];
    float wih[IN_DIM];
#pragma unroll
    for (int k = 0; k < IN_DIM; ++k) wih[k] = w_ih[g * IN_DIM + k];

    if (g < HID) h_sh[g] = 0.0f;
    float c = 0.0f;
    __syncthreads();

    for (int t = 0; t < T_STEPS; ++t) {
        __syncthreads();
        if (g < IN_DIM) xs[g] = x255[t * IN_DIM + g];
        __syncthreads();
        float a0 = bsum, a1 = 0.0f, a2 = 0.0f, a3 = 0.0f;
#pragma unroll
        for (int k = 0; k < IN_DIM; ++k) a0 += wih[k] * xs[k];

        const float4* __restrict__ h4 = reinterpret_cast<const float4*>(h_sh);
#pragma unroll
        for (int k = 0; k < HID / 4; ++k) {
            float4 hv = h4[k];
            a0 += wv[k].x * hv.x;
            a1 += wv[k].y * hv.y;
            a2 += wv[k].z * hv.z;
            a3 += wv[k].w * hv.w;
        }
        float pre = (a0 + a1) + (a2 + a3);
        float a = (quad == 2) ? tanh_fast(pre) : sigm(pre);
        act_sh[g] = a;
        __syncthreads();

        if (g < HID) {
            float iv = act_sh[g];
            float fv = act_sh[HID + g];
            float gv = act_sh[2 * HID + g];
            float ov = act_sh[3 * HID + g];
            c = fv * c + iv * gv;
            float h = ov * tanh_fast(c);
            h_sh[g] = h;
            hs[t * HID + g] = h;
        }
        __syncthreads();
    }
}

// ---------------------------------------------------------------------------
// Kernel 3: final FC — out[t, o] = dot(hs[t, :], w_fc[o, :]) + b_fc[o]
// ---------------------------------------------------------------------------
__global__ __launch_bounds__(256) void k_fc(const float* __restrict__ hs,
                                            const float* __restrict__ w_fc,
                                            const float* __restrict__ b_fc,
                                            float* __restrict__ out) {
    const int idx = blockIdx.x * blockDim.x + threadIdx.x;
    if (idx >= T_STEPS * OUT_DIM) return;
    const int t = idx / OUT_DIM;
    const int o = idx - t * OUT_DIM;
    const float* __restrict__ hrow = hs + t * HID;
    const float* __restrict__ wrow = w_fc + o * HID;
    float acc = b_fc[o];
#pragma unroll 8
    for (int k = 0; k < HID; ++k) acc += hrow[k] * wrow[k];
    out[idx] = acc;
}

// ---------------------------------------------------------------------------
extern "C" void kernel_launch(void* const* d_in, const int* in_sizes, int n_in,
                              void* d_out, int out_size, void* d_ws, size_t ws_size,
                              hipStream_t stream) {
    const float* x    = (const float*)d_in[0];  // [B, T, I]
    const float* w_ih = (const float*)d_in[1];  // [4H, I]
    const float* w_hh = (const float*)d_in[2];  // [4H, H]
    const float* b_ih = (const float*)d_in[3];  // [4H]
    const float* b_hh = (const float*)d_in[4];  // [4H]
    const float* w_fc = (const float*)d_in[5];  // [OUT, H]
    const float* b_fc = (const float*)d_in[6];  // [OUT]
    float* out = (float*)d_out;                 // [T, OUT]

    // Only batch element B-1 is observable in the reference output.
    const float* x255 = x + (size_t)(BATCH - 1) * T_STEPS * IN_DIM;

    float* hs = (float*)d_ws;                                  // 4096*128 f32 = 2 MB
    float* gxbuf = hs + (size_t)T_STEPS * HID;                 // 4096*512 f32 = 8 MB
    const size_t need_full = (size_t)(T_STEPS * HID + T_STEPS * GATES) * sizeof(float);

    if (ws_size >= need_full) {
        k_inproj<<<T_STEPS, GATES, 0, stream>>>(x255, w_ih, b_ih, b_hh, gxbuf);
        k_scan_mfma<<<1, GATES, 0, stream>>>(gxbuf, w_hh, hs);
    } else {
        k_scan_valu<<<1, GATES, 0, stream>>>(w_hh, hs, x255, w_ih, b_ih, b_hh);
    }

    const int n = T_STEPS * OUT_DIM;
    k_fc<<<(n + 255) / 256, 256, 0, stream>>>(hs, w_fc, b_fc, out);
}

// Round 5
// 2374.916 us; speedup vs baseline: 1.4197x; 1.2959x over previous
//
#include <hip/hip_runtime.h>
#include <hip/hip_bf16.h>
#include <math.h>

// Problem constants
#define BATCH   256
#define T_STEPS 4096
#define IN_DIM  28
#define HID     128
#define GATES   512   // 4*HID
#define OUT_DIM 10

typedef short bf16x8 __attribute__((ext_vector_type(8)));  // 8 bf16 in 4 VGPRs
typedef float f32x4  __attribute__((ext_vector_type(4)));

__device__ __forceinline__ float frcp_fast(float x) {
    return __builtin_amdgcn_rcpf(x);
}

__device__ __forceinline__ float sigm(float x) {
    return frcp_fast(1.0f + __expf(-x));
}

__device__ __forceinline__ float tanh_fast(float x) {
    // tanh(x) = sign(x) * (1 - e) / (1 + e), e = exp(-2|x|)  (no overflow)
    float ax = fabsf(x);
    float e  = __expf(-2.0f * ax);
    float r  = (1.0f - e) * frcp_fast(1.0f + e);
    return copysignf(r, x);
}

__device__ __forceinline__ unsigned short f2bf(float f) {
    __hip_bfloat16 h = __float2bfloat16(f);   // RNE
    return __builtin_bit_cast(unsigned short, h);
}
__device__ __forceinline__ float bf2f(unsigned short u) {
    return __bfloat162float(__builtin_bit_cast(__hip_bfloat16, u));
}

// ---------------------------------------------------------------------------
// Kernel 1: input projection for batch element 255, UNIT-MAJOR output:
// gx2[t, u, gt] = dot(x255[t,:], w_ih[gt*128+u,:]) + b_ih[..] + b_hh[..]
// so the scan kernel reads one float4 per (t, unit).
// ---------------------------------------------------------------------------
__global__ __launch_bounds__(GATES) void k_inproj(const float* __restrict__ x255,
                                                  const float* __restrict__ w_ih,
                                                  const float* __restrict__ b_ih,
                                                  const float* __restrict__ b_hh,
                                                  float* __restrict__ gx2) {
    const int t = blockIdx.x;
    const int g = threadIdx.x;          // gate row 0..511 (i|f|g|o blocks of 128)
    const int unit = g & (HID - 1);
    const int quad = g >> 7;
    __shared__ float xs[IN_DIM];
    if (g < IN_DIM) xs[g] = x255[t * IN_DIM + g];
    __syncthreads();
    float acc = b_ih[g] + b_hh[g];
    const float* __restrict__ wr = w_ih + g * IN_DIM;
#pragma unroll
    for (int k = 0; k < IN_DIM; ++k) acc += wr[k] * xs[k];
    gx2[t * GATES + unit * 4 + quad] = acc;
}

// ---------------------------------------------------------------------------
// Kernel 2 (main): MFMA LSTM scan — 512 threads (8 waves), unit-major.
//
// Wave w owns hidden units [16w, 16w+16). 4 A-tiles = gate types i/f/g/o of
// those units. B packs h_hi in EVEN columns, h_lo in ODD columns: one MFMA
// leg computes both split halves as separate D columns.
//
// Lane decode (R4 bugfix): lane l holds D column cidx=l&15, rows q*4+{0..3}
// in acc regs. r_sel = (cidx>>1)&3 is invariant under cidx^1, so pair lanes
// (l, l^1) finalize the SAME unit and __shfl_xor(v,1) sums that unit's
// hi-partial + lo-partial. (R4 had r_sel=cidx&3: pairs mixed partials of
// ADJACENT units -> ~1e-3/step misattribution -> 4.7e-2 after 4096 steps.)
// The pair-sum is correct under any consistent B/D column permutation; row
// mappings are R3-verified, so no unverified layout assumption remains.
//
// Every lane does the full activation + c/h update for its unit (4x
// replicated); one writer lane per unit stores h_hi/h_lo/hs. Double-buffered
// h -> ONE barrier per step.
// ---------------------------------------------------------------------------
__global__ __attribute__((amdgpu_flat_work_group_size(512, 512),
                          amdgpu_waves_per_eu(2, 2)))
void k_scan_mfma(const float* __restrict__ gx2,
                 const float* __restrict__ w_hh,
                 float* __restrict__ hs) {
    const int tid   = threadIdx.x;
    const int w     = tid >> 6;         // wave 0..7
    const int l     = tid & 63;         // lane 0..63
    const int q     = l >> 4;           // k-group / row-group 0..3
    const int cidx  = l & 15;           // D column this lane reads
    const int par   = cidx & 1;         // 0: loads/reads hi-partial, 1: lo
    const int r_sel = (cidx >> 1) & 3;  // acc reg = unit within q-group (pair-invariant!)
    const int ubase = w * 16;
    const int u     = ubase + q * 4 + r_sel;   // unit this lane finalizes
    const bool writer = (par == 0) && (cidx < 8);  // cidx in {0,2,4,6}: one per unit

    __shared__ __align__(16) unsigned short h_hi[2][HID];
    __shared__ __align__(16) unsigned short h_lo[2][HID];

    // ---- one-time: A-frags wf[gate_type][kt] (64 VGPRs) ----
    // lane l holds A row = ubase + cidx (within gate-type block),
    //              k     = kt*32 + q*8 + j
    bf16x8 wf[4][4];
#pragma unroll
    for (int gt = 0; gt < 4; ++gt) {
        const int row = gt * HID + ubase + cidx;
        const float* __restrict__ wr = w_hh + row * HID;
#pragma unroll
        for (int kt = 0; kt < 4; ++kt) {
            const int k0 = kt * 32 + q * 8;
            bf16x8 v;
#pragma unroll
            for (int j = 0; j < 8; ++j) v[j] = (short)f2bf(wr[k0 + j]);
            wf[gt][kt] = v;
        }
    }

    if (tid < HID) {
        h_hi[0][tid] = 0; h_hi[1][tid] = 0;
        h_lo[0][tid] = 0; h_lo[1][tid] = 0;
    }
    float c = 0.0f;                      // cell state (4x replicated per unit)
    // parity-selected source for this lane's B-frags
    const unsigned short* __restrict__ hsrc = par ? &h_lo[0][0] : &h_hi[0][0];

    float4 gnext = *reinterpret_cast<const float4*>(gx2 + u * 4);  // t=0
    __syncthreads();

    for (int t = 0; t < T_STEPS; ++t) {
        const int rb = (t & 1) ^ 1;      // read buffer (h_{t-1}); t=0 reads zeroed buf 1
        const int wb = t & 1;            // write buffer (h_t)

        // B-frags: even cols h_hi, odd cols h_lo (broadcast b128 reads)
        bf16x8 bf[4];
#pragma unroll
        for (int kt = 0; kt < 4; ++kt)
            bf[kt] = *reinterpret_cast<const bf16x8*>(&hsrc[rb * HID + kt * 32 + q * 8]);

        // 16 MFMAs: 4 gate-types x 4 k-tiles, single leg
        f32x4 acc[4];
#pragma unroll
        for (int gt = 0; gt < 4; ++gt) {
            f32x4 a = {0.f, 0.f, 0.f, 0.f};
#pragma unroll
            for (int kt = 0; kt < 4; ++kt)
                a = __builtin_amdgcn_mfma_f32_16x16x32_bf16(wf[gt][kt], bf[kt], a, 0, 0, 0);
            acc[gt] = a;
        }

        float4 gcur = gnext;
        if (t + 1 < T_STEPS)
            gnext = *reinterpret_cast<const float4*>(gx2 + (t + 1) * GATES + u * 4);

        // per-gate-type: pick this lane's reg (static select), sum hi+lo pair
        float pre[4];
#pragma unroll
        for (int gt = 0; gt < 4; ++gt) {
            float v = 0.0f;
#pragma unroll
            for (int r = 0; r < 4; ++r)
                if (r == r_sel) v = acc[gt][r];
            v += __shfl_xor(v, 1);       // same-unit hi-partial + lo-partial
            pre[gt] = v;
        }
        pre[0] += gcur.x; pre[1] += gcur.y; pre[2] += gcur.z; pre[3] += gcur.w;

        // full LSTM cell update in-lane (gate order i, f, g, o)
        float iv = sigm(pre[0]);
        float fv = sigm(pre[1]);
        float gv = tanh_fast(pre[2]);
        float ov = sigm(pre[3]);
        c = fv * c + iv * gv;
        float h = ov * tanh_fast(c);

        if (writer) {                    // one writer per unit
            unsigned short hi = f2bf(h);
            h_hi[wb][u] = hi;
            h_lo[wb][u] = f2bf(h - bf2f(hi));   // residual -> h exact to ~2^-17
            hs[t * HID + u] = h;
        }
        __syncthreads();                 // h_t visible; WAR safe via double buffer
    }
}

// ---------------------------------------------------------------------------
// Fallback scan (fused input projection, f32 VALU) — only if d_ws too small.
// ---------------------------------------------------------------------------
__global__ __launch_bounds__(GATES) void k_scan_valu(const float* __restrict__ w_hh,
                                                     float* __restrict__ hs,
                                                     const float* __restrict__ x255,
                                                     const float* __restrict__ w_ih,
                                                     const float* __restrict__ b_ih,
                                                     const float* __restrict__ b_hh) {
    const int g    = threadIdx.x;
    const int quad = g >> 7;

    __shared__ float h_sh[HID];
    __shared__ float act_sh[GATES];
    __shared__ float xs[IN_DIM];

    float4 wv[HID / 4];
    const float4* __restrict__ wrow = reinterpret_cast<const float4*>(w_hh + g * HID);
#pragma unroll
    for (int k = 0; k < HID / 4; ++k) wv[k] = wrow[k];

    float bsum = b_ih[g] + b_hh[g];
    float wih[IN_DIM];
#pragma unroll
    for (int k = 0; k < IN_DIM; ++k) wih[k] = w_ih[g * IN_DIM + k];

    if (g < HID) h_sh[g] = 0.0f;
    float c = 0.0f;
    __syncthreads();

    for (int t = 0; t < T_STEPS; ++t) {
        __syncthreads();
        if (g < IN_DIM) xs[g] = x255[t * IN_DIM + g];
        __syncthreads();
        float a0 = bsum, a1 = 0.0f, a2 = 0.0f, a3 = 0.0f;
#pragma unroll
        for (int k = 0; k < IN_DIM; ++k) a0 += wih[k] * xs[k];

        const float4* __restrict__ h4 = reinterpret_cast<const float4*>(h_sh);
#pragma unroll
        for (int k = 0; k < HID / 4; ++k) {
            float4 hv = h4[k];
            a0 += wv[k].x * hv.x;
            a1 += wv[k].y * hv.y;
            a2 += wv[k].z * hv.z;
            a3 += wv[k].w * hv.w;
        }
        float pre = (a0 + a1) + (a2 + a3);
        float a = (quad == 2) ? tanh_fast(pre) : sigm(pre);
        act_sh[g] = a;
        __syncthreads();

        if (g < HID) {
            float iv = act_sh[g];
            float fv = act_sh[HID + g];
            float gv = act_sh[2 * HID + g];
            float ov = act_sh[3 * HID + g];
            c = fv * c + iv * gv;
            float h = ov * tanh_fast(c);
            h_sh[g] = h;
            hs[t * HID + g] = h;
        }
        __syncthreads();
    }
}

// ---------------------------------------------------------------------------
// Kernel 3: final FC — out[t, o] = dot(hs[t, :], w_fc[o, :]) + b_fc[o]
// ---------------------------------------------------------------------------
__global__ __launch_bounds__(256) void k_fc(const float* __restrict__ hs,
                                            const float* __restrict__ w_fc,
                                            const float* __restrict__ b_fc,
                                            float* __restrict__ out) {
    const int idx = blockIdx.x * blockDim.x + threadIdx.x;
    if (idx >= T_STEPS * OUT_DIM) return;
    const int t = idx / OUT_DIM;
    const int o = idx - t * OUT_DIM;
    const float* __restrict__ hrow = hs + t * HID;
    const float* __restrict__ wrow = w_fc + o * HID;
    float acc = b_fc[o];
#pragma unroll 8
    for (int k = 0; k < HID; ++k) acc += hrow[k] * wrow[k];
    out[idx] = acc;
}

// ---------------------------------------------------------------------------
extern "C" void kernel_launch(void* const* d_in, const int* in_sizes, int n_in,
                              void* d_out, int out_size, void* d_ws, size_t ws_size,
                              hipStream_t stream) {
    const float* x    = (const float*)d_in[0];  // [B, T, I]
    const float* w_ih = (const float*)d_in[1];  // [4H, I]
    const float* w_hh = (const float*)d_in[2];  // [4H, H]
    const float* b_ih = (const float*)d_in[3];  // [4H]
    const float* b_hh = (const float*)d_in[4];  // [4H]
    const float* w_fc = (const float*)d_in[5];  // [OUT, H]
    const float* b_fc = (const float*)d_in[6];  // [OUT]
    float* out = (float*)d_out;                 // [T, OUT]

    // Only batch element B-1 is observable in the reference output.
    const float* x255 = x + (size_t)(BATCH - 1) * T_STEPS * IN_DIM;

    float* hs = (float*)d_ws;                                  // 4096*128 f32 = 2 MB
    float* gx2 = hs + (size_t)T_STEPS * HID;                   // 4096*512 f32 = 8 MB (unit-major)
    const size_t need_full = (size_t)(T_STEPS * HID + T_STEPS * GATES) * sizeof(float);

    if (ws_size >= need_full) {
        k_inproj<<<T_STEPS, GATES, 0, stream>>>(x255, w_ih, b_ih, b_hh, gx2);
        k_scan_mfma<<<1, GATES, 0, stream>>>(gx2, w_hh, hs);
    } else {
        k_scan_valu<<<1, GATES, 0, stream>>>(w_hh, hs, x255, w_ih, b_ih, b_hh);
    }

    const int n = T_STEPS * OUT_DIM;
    k_fc<<<(n + 255) / 256, 256, 0, stream>>>(hs, w_fc, b_fc, out);
}